// Round 12
// baseline (462.430 us; speedup 1.0000x reference)
//
#include <hip/hip_runtime.h>
#include <hip/hip_bf16.h>

typedef __hip_bfloat16 bf16;
typedef float floatx4 __attribute__((ext_vector_type(4)));
typedef short bf16x8 __attribute__((ext_vector_type(8)));

#define B_      2
#define S_      2048
#define IN_     512
#define E_      1024
#define INNER_  2048
#define NH_     4
#define DH_     512
#define T_      (B_*S_)      // 4096 tokens
#define EPS_CELL 1e-6f
#define LN_EPS_  1e-5f
#define LS      72           // padded LDS row stride (shorts) for non-async kernels

__device__ inline float b2f(bf16 x){ return __bfloat162float(x); }
__device__ inline bf16  f2b(float x){ return __float2bfloat16(x); }
__device__ inline float us2f(unsigned short u){ union{unsigned int i; float f;} v; v.i = ((unsigned int)u)<<16; return v.f; }
__device__ inline float u2f(unsigned int u){ union{unsigned int i; float f;} v; v.i = u; return v.f; }
__device__ inline unsigned short f2bu(float x){ bf16 t = __float2bfloat16(x); unsigned short r; __builtin_memcpy(&r,&t,2); return r; }
__device__ inline void stv(bf16* p, float v){ *p = f2b(v); }
__device__ inline void stv(float* p, float v){ *p = v; }

// ---- async 16B global->LDS copy (wave-uniform base + lane*16 pattern) ----
typedef __attribute__((address_space(3))) unsigned int lds_u32_t;
typedef __attribute__((address_space(1))) const unsigned int glb_u32_t;
__device__ __forceinline__ void cp_async16(const bf16* g, short* l){
  __builtin_amdgcn_global_load_lds((glb_u32_t*)(const void*)g,
                                   (lds_u32_t*)(void*)l, 16, 0, 0);
}
// swizzled LDS offset (shorts) for Nx64 tile: row-dense, chunk XOR row&7
__device__ __forceinline__ int so_(int row, int c8){ return row*64 + (((c8) ^ (row&7))<<3); }
// epilogue repack offset for Nx128-short tile: chunk XOR row&15
__device__ __forceinline__ int eo_(int row, int ch){ return row*128 + (((ch) ^ (row&15))<<3); }

// stage rows of a {64,128}x64-short tile (row stride `stride` in global)
#define STAGE_ASYNC(dst, srcbase, stride, kk) \
  { int slot_ = (kk)*256 + tid; int r_ = slot_>>3; int c8_ = (slot_&7) ^ (r_&7); \
    cp_async16((srcbase) + (size_t)r_*(stride) + c8_*8, &dst[slot_*8]); }

// ---------------- fp32 -> bf16 elementwise convert ----------------
__global__ __launch_bounds__(256) void convert_bf16(const float* __restrict__ X,
    bf16* __restrict__ Y, int n8){
  int i = blockIdx.x*256 + threadIdx.x;
  if (i >= n8) return;
  const float4* p = (const float4*)(X) + i*2;
  float4 a = p[0], b = p[1];
  ushort4 o0, o1;
  o0.x=f2bu(a.x); o0.y=f2bu(a.y); o0.z=f2bu(a.z); o0.w=f2bu(a.w);
  o1.x=f2bu(b.x); o1.y=f2bu(b.y); o1.z=f2bu(b.z); o1.w=f2bu(b.w);
  ushort4* q = (ushort4*)(Y) + i*2;
  q[0]=o0; q[1]=o1;
}

// ---------------- W[K,N] fp32 -> Wt[N,K] bf16 (64x64 LDS tiles) ----------------
__global__ __launch_bounds__(256) void transpose_conv_w(const float* __restrict__ W,
    bf16* __restrict__ Wt, int K, int N){
  int n0 = blockIdx.x*64, k0 = blockIdx.y*64;
  __shared__ float tl[64][65];
  int tid = threadIdx.x;
  #pragma unroll
  for (int i=0;i<4;i++){
    int idx = tid + i*256; int r = idx>>4, c4 = idx&15;
    float4 v = *(const float4*)(W + (size_t)(k0+r)*N + n0 + c4*4);
    tl[r][c4*4+0]=v.x; tl[r][c4*4+1]=v.y; tl[r][c4*4+2]=v.z; tl[r][c4*4+3]=v.w;
  }
  __syncthreads();
  #pragma unroll
  for (int i=0;i<4;i++){
    int idx = tid + i*256; int rn = idx>>4, c4 = idx&15;
    ushort4 o;
    o.x=f2bu(tl[c4*4+0][rn]); o.y=f2bu(tl[c4*4+1][rn]);
    o.z=f2bu(tl[c4*4+2][rn]); o.w=f2bu(tl[c4*4+3][rn]);
    *(ushort4*)(Wt + (size_t)(n0+rn)*K + k0 + c4*4) = o;
  }
}

// ---------------- MFMA GEMM: C[M,N] = A[M,K] @ Bt[N,K]^T + bias ----------------
// 1-D grid MM*NN; per-XCD m-stripe swizzle. Vectorized LDS-repack epilogue.
__global__ __launch_bounds__(256) void mfma_gemm(const bf16* __restrict__ A,
    const bf16* __restrict__ Bt, const float* __restrict__ bias, bf16* __restrict__ C,
    int Kd, int lda, int ldc, int NN){
  int bid = blockIdx.x;
  int MM = gridDim.x / NN;
  int mPerX = MM >> 3;
  int xcd = bid & 7, seq = bid >> 3;
  int nb = seq % NN, mb = xcd*mPerX + seq / NN;
  int n0 = nb*128, m0 = mb*128;
  __shared__ __align__(16) short smem[128*128];   // As | Bs ; reused for C repack
  short* As = smem;
  short* Bs = smem + 128*64;
  int tid = threadIdx.x;
  int w = tid>>6, l = tid&63, lq = l>>4, lr = l&15;
  int wm = (w>>1)*64, wn = (w&1)*64;
  const bf16* Abase = A + (size_t)m0*lda;
  const bf16* Bbase = Bt + (size_t)n0*Kd;
  floatx4 acc[4][4];
  #pragma unroll
  for (int mi=0;mi<4;mi++){
    #pragma unroll
    for (int ni=0;ni<4;ni++) acc[mi][ni] = (floatx4){0.f,0.f,0.f,0.f};
  }
  for (int k0=0; k0<Kd; k0+=64){
    __syncthreads();
    #pragma unroll
    for (int kk=0;kk<4;kk++){
      STAGE_ASYNC(As, Abase + k0, lda, kk);
      STAGE_ASYNC(Bs, Bbase + k0, Kd, kk);
    }
    __syncthreads();
    #pragma unroll
    for (int ks=0; ks<2; ks++){
      bf16x8 af[4], bfr[4];
      #pragma unroll
      for (int mi=0;mi<4;mi++) af[mi] = *(const bf16x8*)&As[so_(wm+mi*16+lr, ks*4+lq)];
      #pragma unroll
      for (int ni=0;ni<4;ni++) bfr[ni] = *(const bf16x8*)&Bs[so_(wn+ni*16+lr, ks*4+lq)];
      #pragma unroll
      for (int mi=0;mi<4;mi++){
        #pragma unroll
        for (int ni=0;ni<4;ni++)
          acc[mi][ni] = __builtin_amdgcn_mfma_f32_16x16x32_bf16(af[mi], bfr[ni], acc[mi][ni], 0,0,0);
      }
    }
  }
  float bb[4];
  #pragma unroll
  for (int ni=0;ni<4;ni++) bb[ni] = bias[n0 + wn + ni*16 + lr];
  __syncthreads();   // staging LDS dead -> reuse for C repack
  #pragma unroll
  for (int mi=0;mi<4;mi++){
    #pragma unroll
    for (int ni=0;ni<4;ni++){
      int coll = wn + ni*16 + lr;
      int ch = coll>>3, off = coll&7;
      #pragma unroll
      for (int r=0;r<4;r++){
        int rowl = wm + mi*16 + lq*4 + r;
        smem[rowl*128 + (((ch) ^ (rowl&15))<<3) + off] = (short)f2bu(acc[mi][ni][r] + bb[ni]);
      }
    }
  }
  __syncthreads();
  #pragma unroll
  for (int i=0;i<8;i++){
    int slot = i*256 + tid;
    int r = slot >> 4, c8 = slot & 15;
    uint4 val = *(const uint4*)&smem[eo_(r, c8)];
    *(uint4*)(C + (size_t)(m0+r)*ldc + n0 + c8*8) = val;
  }
}

// ---------------- layernorm over rows of length E_ (opt. fused add) ----------------
template<typename OutT>
__global__ __launch_bounds__(256) void ln_rows(const bf16* __restrict__ X,
    const bf16* __restrict__ Xadd, const float* __restrict__ w, OutT* __restrict__ Y){
  int row = blockIdx.x, tid = threadIdx.x;
  size_t base = (size_t)row*E_;
  float vals[4], s=0.f, s2=0.f;
  #pragma unroll
  for (int e=0;e<4;e++){
    int c = e*256+tid;
    float v = b2f(X[base+c]);
    if (Xadd) v += b2f(Xadd[base+c]);
    vals[e]=v; s+=v; s2+=v*v;
  }
  __shared__ float sa[256], sb[256];
  sa[tid]=s; sb[tid]=s2; __syncthreads();
  for (int off=128; off>0; off>>=1){
    if (tid<off){ sa[tid]+=sa[tid+off]; sb[tid]+=sb[tid+off]; }
    __syncthreads();
  }
  float mean = sa[0]*(1.f/E_);
  float var  = sb[0]*(1.f/E_) - mean*mean;
  float rstd = rsqrtf(var + LN_EPS_);
  #pragma unroll
  for (int e=0;e<4;e++){
    int c = e*256+tid;
    stv(&Y[base+c], (vals[e]-mean)*rstd*w[c]);
  }
}

// ---------------- fused conv(K=4)+SiLU, q/k/v, and gate partial dots ----------------
// block = 256 consecutive channels of one token; xca shared via LDS.
// gate partials reduced across block, atomically added to igo/fgo (pre-zeroed).
__global__ __launch_bounds__(256) void conv_headwise(const bf16* __restrict__ up,
    const float* __restrict__ cw, const float* __restrict__ cb,
    const float* __restrict__ qw, const float* __restrict__ qb,
    const float* __restrict__ kw, const float* __restrict__ kb,
    const float* __restrict__ vw, const float* __restrict__ vb,
    const float* __restrict__ igw, const float* __restrict__ fgw,
    bf16* __restrict__ xca, bf16* __restrict__ q, bf16* __restrict__ k,
    bf16* __restrict__ v, float* __restrict__ igo, float* __restrict__ fgo){
  size_t gid = (size_t)blockIdx.x*256 + threadIdx.x;
  int c = (int)(gid & (INNER_-1));
  size_t bs = gid >> 11;
  int s = (int)(bs & (S_-1));
  int bbat = (int)(bs >> 11);
  float acc = cb[c];
  #pragma unroll
  for (int t=0;t<4;t++){
    int sp = s-3+t;
    if (sp>=0) acc += b2f(up[(bs + (size_t)(t-3))*(size_t)(2*INNER_) + c]) * cw[c*4+t];
  }
  float xcv = acc/(1.f+expf(-acc));
  __shared__ float xcs[256];
  xcs[threadIdx.x] = xcv;
  xca[gid] = f2b(xcv);
  __syncthreads();
  int o = c&3;
  int lb = threadIdx.x & ~3;
  int hw = c>>2;
  float aq=qb[c], ak=kb[c], av=vb[c];
  size_t mb = bs*(size_t)(2*INNER_) + (size_t)(c&~3);
  #pragma unroll
  for (int d=0; d<4; d++){
    float xc = xcs[lb+d];
    float xm = b2f(up[mb+d]);
    int wi = hw*16 + o*4 + d;   // w[h][o][d]
    aq += xc*qw[wi]; ak += xc*kw[wi]; av += xm*vw[wi];
  }
  q[gid]=f2b(aq); k[gid]=f2b(ak); v[gid]=f2b(av);
  // ---- gate partials: if_in = [q|k|v] row dotted with igw/fgw columns ----
  const float4* igr = (const float4*)igw;
  const float4* fgr = (const float4*)fgw;
  float4 wiq = igr[c], wik = igr[INNER_+c], wiv = igr[2*INNER_+c];
  float4 wfq = fgr[c], wfk = fgr[INNER_+c], wfv = fgr[2*INNER_+c];
  float g8[8];
  g8[0] = aq*wiq.x + ak*wik.x + av*wiv.x;
  g8[1] = aq*wiq.y + ak*wik.y + av*wiv.y;
  g8[2] = aq*wiq.z + ak*wik.z + av*wiv.z;
  g8[3] = aq*wiq.w + ak*wik.w + av*wiv.w;
  g8[4] = aq*wfq.x + ak*wfk.x + av*wfv.x;
  g8[5] = aq*wfq.y + ak*wfk.y + av*wfv.y;
  g8[6] = aq*wfq.z + ak*wfk.z + av*wfv.z;
  g8[7] = aq*wfq.w + ak*wfk.w + av*wfv.w;
  #pragma unroll
  for (int off=32; off>0; off>>=1){
    #pragma unroll
    for (int n=0;n<8;n++) g8[n] += __shfl_xor(g8[n], off);
  }
  __shared__ float red[8][4];
  int wv2 = threadIdx.x >> 6;
  if ((threadIdx.x & 63) == 0){
    #pragma unroll
    for (int n=0;n<8;n++) red[n][wv2] = g8[n];
  }
  __syncthreads();
  if (threadIdx.x < 8){
    float sum = red[threadIdx.x][0] + red[threadIdx.x][1]
              + red[threadIdx.x][2] + red[threadIdx.x][3];
    int n = threadIdx.x & 3;
    float* dst = (threadIdx.x < 4) ? igo : fgo;
    atomicAdd(&dst[((size_t)(bbat*NH_+n))*S_ + s], sum);
  }
}

// ---------------- per-head scan (bias fused): F=cumsum(logsig(fg+b)); a=ig+b-F ----
__global__ __launch_bounds__(256) void scan8(const float* __restrict__ igp,
    const float* __restrict__ fgp, const float* __restrict__ igb,
    const float* __restrict__ fgb, float* __restrict__ ap,
    float* __restrict__ Mp, float* __restrict__ flp, float* __restrict__ rowsum){
  int h = blockIdx.x, tid = threadIdx.x;
  const float* fg = fgp + (size_t)h*S_;
  const float* ig = igp + (size_t)h*S_;
  float bi = igb[h & 3], bf = fgb[h & 3];
  int base = tid*8;
  float loc[8], run = 0.f;
  #pragma unroll
  for (int e=0;e<8;e++){
    float x = fg[base+e] + bf;
    float ls = fminf(x,0.f) - log1pf(expf(-fabsf(x)));
    run += ls; loc[e] = run;
  }
  __shared__ float sd[256];
  sd[tid]=run; __syncthreads();
  if (tid==0){ float r=0.f; for(int t=0;t<256;t++){ float t0=sd[t]; sd[t]=r; r+=t0; } }
  __syncthreads();
  float off = sd[tid];
  float lm[8], rm = -3e38f;
  #pragma unroll
  for (int e=0;e<8;e++){
    float F = loc[e]+off; loc[e]=F;
    float aj = (ig[base+e] + bi) - F;
    ap[(size_t)h*S_+base+e]=aj;
    rm = fmaxf(rm, aj); lm[e]=rm;
  }
  __syncthreads();
  sd[tid]=rm; __syncthreads();
  if (tid==0){ float r=-3e38f; for(int t=0;t<256;t++){ float t0=sd[t]; sd[t]=r; r=fmaxf(r,t0); } }
  __syncthreads();
  float offm = sd[tid];
  #pragma unroll
  for (int e=0;e<8;e++){
    float M = fmaxf(lm[e], offm);
    Mp[(size_t)h*S_+base+e]=M;
    flp[(size_t)h*S_+base+e]=expf(-loc[e]-M);
    rowsum[(size_t)h*S_+base+e]=0.f;
  }
}

// ---------------- v (b,s,n*DH+d) -> vT (h, d, s) ----------------
__global__ __launch_bounds__(256) void transpose_v(const bf16* __restrict__ v,
    bf16* __restrict__ vT){
  int sb = blockIdx.x, db = blockIdx.y, h = blockIdx.z;
  int b = h >> 2, n = h & 3;
  int s0 = sb*64, d0 = db*64;
  __shared__ short tl[64*LS];
  int tid = threadIdx.x;
  #pragma unroll
  for (int i=0;i<2;i++){
    int vv = tid + i*256; int r = vv>>3, c8 = vv&7;
    uint4 x = *(const uint4*)(v + (size_t)(b*S_+s0+r)*INNER_ + n*DH_ + d0 + c8*8);
    *(uint4*)&tl[r*LS + c8*8] = x;
  }
  __syncthreads();
  #pragma unroll
  for (int i=0;i<2;i++){
    int vv = tid + i*256; int r = vv>>3, c8 = vv&7;   // r = local d, c8 = s-chunk
    unsigned short tmp[8];
    #pragma unroll
    for (int e=0;e<8;e++) tmp[e] = (unsigned short)tl[(c8*8+e)*LS + r];
    uint4 o; __builtin_memcpy(&o, tmp, 16);
    *(uint4*)(vT + ((size_t)h*DH_ + d0 + r)*S_ + s0 + c8*8) = o;
  }
}

// ---------------- W = (Q K^T)*scale*exp(a_j - M_i), causal; + rowsums ----------------
// 64x128 i x j tiles, lower triangle; grid 8*272, h = bid&7 (XCD-pinned).
__global__ __launch_bounds__(256) void qk_decay_kernel(const bf16* __restrict__ qg,
    const bf16* __restrict__ kg, const float* __restrict__ ap,
    const float* __restrict__ Mp, float* __restrict__ rowsum, bf16* __restrict__ W){
  int h = blockIdx.x & 7;
  int t = 271 - (blockIdx.x >> 3);
  int p = (int)((sqrtf(4.f*t+1.f)-1.f)*0.5f);
  while ((p+1)*(p+2) <= t) p++;
  while (p*(p+1) > t) p--;
  int r0 = t - p*(p+1);
  int nj = p + 1;
  int it = 2*p + (r0 >= nj ? 1 : 0);
  int tj = r0 >= nj ? r0 - nj : r0;
  int b = h >> 2, n = h & 3;
  int i0 = it*64, j0 = tj*128;
  __shared__ __align__(16) short smem[64*64 + 128*64];  // Qs | Ks ; reused for W repack
  short* Qs = smem;
  short* Ks = smem + 64*64;
  __shared__ float a_s[128], m_s[64];
  int tid = threadIdx.x;
  if (tid < 128) a_s[tid] = ap[(size_t)h*S_ + j0 + tid];
  if (tid < 64)  m_s[tid] = Mp[(size_t)h*S_ + i0 + tid];
  int w = tid>>6, l = tid&63, lq = l>>4, lr = l&15;
  int wm = (w>>1)*32, wn = (w&1)*64;
  const bf16* Qbase = qg + (size_t)(b*S_+i0)*INNER_ + n*DH_;
  const bf16* Kbase = kg + (size_t)(b*S_+j0)*INNER_ + n*DH_;
  floatx4 acc[2][4];
  #pragma unroll
  for (int mi=0;mi<2;mi++){
    #pragma unroll
    for (int ni=0;ni<4;ni++) acc[mi][ni] = (floatx4){0.f,0.f,0.f,0.f};
  }
  for (int d0=0; d0<DH_; d0+=64){
    __syncthreads();
    STAGE_ASYNC(Qs, Qbase + d0, INNER_, 0);
    STAGE_ASYNC(Qs, Qbase + d0, INNER_, 1);
    #pragma unroll
    for (int kk=0;kk<4;kk++){
      STAGE_ASYNC(Ks, Kbase + d0, INNER_, kk);
    }
    __syncthreads();
    #pragma unroll
    for (int ks=0; ks<2; ks++){
      bf16x8 af[2], bfr[4];
      #pragma unroll
      for (int mi=0;mi<2;mi++) af[mi] = *(const bf16x8*)&Qs[so_(wm+mi*16+lr, ks*4+lq)];
      #pragma unroll
      for (int ni=0;ni<4;ni++) bfr[ni] = *(const bf16x8*)&Ks[so_(wn+ni*16+lr, ks*4+lq)];
      #pragma unroll
      for (int mi=0;mi<2;mi++){
        #pragma unroll
        for (int ni=0;ni<4;ni++)
          acc[mi][ni] = __builtin_amdgcn_mfma_f32_16x16x32_bf16(af[mi], bfr[ni], acc[mi][ni], 0,0,0);
      }
    }
  }
  const float scale = 0.04419417382415922f;   // 1/sqrt(512)
  float rpart[2][4];
  #pragma unroll
  for (int mi=0;mi<2;mi++){
    #pragma unroll
    for (int r=0;r<4;r++) rpart[mi][r]=0.f;
  }
  __syncthreads();   // staging LDS dead -> reuse for W repack
  #pragma unroll
  for (int mi=0;mi<2;mi++){
    #pragma unroll
    for (int ni=0;ni<4;ni++){
      int coll = wn + ni*16 + lr;
      int ch = coll>>3, off = coll&7;
      float av = a_s[coll];
      #pragma unroll
      for (int r=0;r<4;r++){
        int rowl = wm + mi*16 + lq*4 + r;
        int gi = i0 + rowl, gj = j0 + coll;
        float wv = 0.f;
        if (gj <= gi) wv = acc[mi][ni][r]*scale*__expf(av-m_s[rowl]);
        smem[rowl*128 + (((ch) ^ (rowl&15))<<3) + off] = (short)f2bu(wv);
        rpart[mi][r] += wv;
      }
    }
  }
  __syncthreads();
  #pragma unroll
  for (int i=0;i<4;i++){
    int slot = i*256 + tid;
    int r = slot >> 4, c8 = slot & 15;
    uint4 val = *(const uint4*)&smem[eo_(r, c8)];
    *(uint4*)(W + ((size_t)h*S_ + i0 + r)*S_ + j0 + c8*8) = val;
  }
  #pragma unroll
  for (int mi=0;mi<2;mi++){
    #pragma unroll
    for (int r=0;r<4;r++){
      float v = rpart[mi][r];
      v += __shfl_xor(v, 1, 16);
      v += __shfl_xor(v, 2, 16);
      v += __shfl_xor(v, 4, 16);
      v += __shfl_xor(v, 8, 16);
      if (lr == 0)
        atomicAdd(&rowsum[(size_t)h*S_ + i0 + wm + mi*16 + lq*4 + r], v);
    }
  }
}

// ---------------- O = (W * inv_row) @ V  (causal k-range), inv fused ----------------
// 64-row i-tiles x 128-d tiles: grid 8*128; h = bid&7 (XCD-pinned); ti descending
__global__ __launch_bounds__(256) void pv_kernel(const bf16* __restrict__ W,
    const bf16* __restrict__ vT, const float* __restrict__ rowsum,
    const float* __restrict__ fl, bf16* __restrict__ O){
  int h = blockIdx.x & 7;
  int s = blockIdx.x >> 3;
  int ti = 31 - (s >> 2), tn = s & 3;
  int b = h >> 2, n = h & 3;
  int i0 = ti*64, d0 = tn*128;
  __shared__ __align__(16) short smem[64*64 + 128*64];  // Ws | Vs ; reused for O repack
  short* Ws = smem;
  short* Vs = smem + 64*64;
  __shared__ float inv_s[64];
  int tid = threadIdx.x;
  if (tid < 64){
    size_t o = (size_t)h*S_ + i0 + tid;
    inv_s[tid] = 1.f/(fmaxf(fabsf(rowsum[o]), fl[o]) + EPS_CELL);
  }
  int w = tid>>6, l = tid&63, lq = l>>4, lr = l&15;
  int wm = (w>>1)*32, wn = (w&1)*64;
  const bf16* Wbase = W + ((size_t)h*S_ + i0)*S_;
  const bf16* Vbase = vT + ((size_t)h*DH_ + d0)*S_;
  floatx4 acc[2][4];
  #pragma unroll
  for (int mi=0;mi<2;mi++){
    #pragma unroll
    for (int ni=0;ni<4;ni++) acc[mi][ni] = (floatx4){0.f,0.f,0.f,0.f};
  }
  int jmax = i0 + 64;
  for (int j0=0; j0<jmax; j0+=64){
    __syncthreads();
    STAGE_ASYNC(Ws, Wbase + j0, S_, 0);
    STAGE_ASYNC(Ws, Wbase + j0, S_, 1);
    #pragma unroll
    for (int kk=0;kk<4;kk++){
      STAGE_ASYNC(Vs, Vbase + j0, S_, kk);
    }
    __syncthreads();
    #pragma unroll
    for (int ks=0; ks<2; ks++){
      bf16x8 af[2], bfr[4];
      #pragma unroll
      for (int mi=0;mi<2;mi++) af[mi] = *(const bf16x8*)&Ws[so_(wm+mi*16+lr, ks*4+lq)];
      #pragma unroll
      for (int ni=0;ni<4;ni++) bfr[ni] = *(const bf16x8*)&Vs[so_(wn+ni*16+lr, ks*4+lq)];
      #pragma unroll
      for (int mi=0;mi<2;mi++){
        #pragma unroll
        for (int ni=0;ni<4;ni++)
          acc[mi][ni] = __builtin_amdgcn_mfma_f32_16x16x32_bf16(af[mi], bfr[ni], acc[mi][ni], 0,0,0);
      }
    }
  }
  __syncthreads();   // staging LDS dead -> reuse for O repack
  #pragma unroll
  for (int mi=0;mi<2;mi++){
    #pragma unroll
    for (int ni=0;ni<4;ni++){
      int dl = wn + ni*16 + lr;
      int ch = dl>>3, off = dl&7;
      #pragma unroll
      for (int r=0;r<4;r++){
        int rowl = wm + mi*16 + lq*4 + r;
        smem[rowl*128 + (((ch) ^ (rowl&15))<<3) + off] = (short)f2bu(acc[mi][ni][r] * inv_s[rowl]);
      }
    }
  }
  __syncthreads();
  #pragma unroll
  for (int i=0;i<4;i++){
    int slot = i*256 + tid;
    int r = slot >> 4, c8 = slot & 15;
    uint4 val = *(const uint4*)&smem[eo_(r, c8)];
    *(uint4*)(O + (size_t)(b*S_ + i0 + r)*INNER_ + n*DH_ + d0 + c8*8) = val;
  }
}

// ---------------- head groupnorm + skip + output gate (in-place into z) ----------
__global__ __launch_bounds__(256) void headnorm_gate(const bf16* __restrict__ h,
    const float* __restrict__ onw, const float* __restrict__ skip,
    const bf16* __restrict__ xca, bf16* __restrict__ up){
  int bid = blockIdx.x;
  int n = bid & 3; int bs = bid >> 2;
  int tid = threadIdx.x;
  size_t hbase = (size_t)bs*INNER_ + n*DH_;
  float v0 = b2f(h[hbase+tid]);
  float v1 = b2f(h[hbase+256+tid]);
  __shared__ float sa[256], sb[256];
  sa[tid]=v0+v1; sb[tid]=v0*v0+v1*v1;
  __syncthreads();
  for (int off=128; off>0; off>>=1){
    if (tid<off){ sa[tid]+=sa[tid+off]; sb[tid]+=sb[tid+off]; }
    __syncthreads();
  }
  float mean = sa[0]*(1.f/DH_);
  float var  = sb[0]*(1.f/DH_) - mean*mean;
  float rstd = rsqrtf(var + LN_EPS_);
  #pragma unroll
  for (int e=0;e<2;e++){
    int dl = e*256+tid; int c = n*DH_+dl;
    float hv = e ? v1 : v0;
    float hn = (hv-mean)*rstd*onw[c];
    float hs = hn + skip[c]*b2f(xca[(size_t)bs*INNER_+c]);
    size_t zoff = (size_t)bs*(2*INNER_) + INNER_ + c;
    float zv = b2f(up[zoff]);
    float sz = zv/(1.f+expf(-zv));
    up[zoff] = f2b(hs*sz);
  }
}

extern "C" void kernel_launch(void* const* d_in, const int* in_sizes, int n_in,
                              void* d_out, int out_size, void* d_ws, size_t ws_size,
                              hipStream_t stream) {
  const float* x      = (const float*)d_in[0];
  const float* w_in   = (const float*)d_in[1];
  const float* b_in   = (const float*)d_in[2];
  const float* ln1_w  = (const float*)d_in[3];
  const float* w_up   = (const float*)d_in[4];
  const float* b_up   = (const float*)d_in[5];
  const float* conv_w = (const float*)d_in[6];
  const float* conv_b = (const float*)d_in[7];
  const float* q_w    = (const float*)d_in[8];
  const float* q_b    = (const float*)d_in[9];
  const float* k_w    = (const float*)d_in[10];
  const float* k_b    = (const float*)d_in[11];
  const float* v_w    = (const float*)d_in[12];
  const float* v_b    = (const float*)d_in[13];
  const float* ig_w   = (const float*)d_in[14];
  const float* ig_b   = (const float*)d_in[15];
  const float* fg_w   = (const float*)d_in[16];
  const float* fg_b   = (const float*)d_in[17];
  const float* onw    = (const float*)d_in[18];
  const float* skip   = (const float*)d_in[19];
  const float* w_down = (const float*)d_in[20];
  const float* b_down = (const float*)d_in[21];
  const float* post_w = (const float*)d_in[22];

  char* p = (char*)d_ws;
  auto alloc = [&](size_t bytes)->void*{ void* r = p; p += (bytes + 255) & ~(size_t)255; return r; };
  bf16* h_in = (bf16*)alloc((size_t)T_*E_*2);        // 8 MB
  bf16* xn   = (bf16*)alloc((size_t)T_*E_*2);        // 8 MB (reused as y later)
  bf16* up   = (bf16*)alloc((size_t)T_*2*INNER_*2);  // 32 MB (x_m | z; z later holds h_gated)
  bf16* xca  = (bf16*)alloc((size_t)T_*INNER_*2);    // 16 MB
  bf16* qb_  = (bf16*)alloc((size_t)T_*INNER_*2);
  bf16* kb_  = (bf16*)alloc((size_t)T_*INNER_*2);
  bf16* vb_  = (bf16*)alloc((size_t)T_*INNER_*2);    // v; later reused as attention O
  bf16* hb_  = (bf16*)alloc((size_t)T_*INNER_*2);    // reused as vT (h,d,s)
  float* igbuf = (float*)alloc((size_t)B_*NH_*S_*4);
  float* fgbuf = (float*)alloc((size_t)B_*NH_*S_*4);
  float* abuf  = (float*)alloc((size_t)B_*NH_*S_*4);
  float* Mbuf  = (float*)alloc((size_t)B_*NH_*S_*4);
  float* flbuf = (float*)alloc((size_t)B_*NH_*S_*4);
  float* rsbuf = (float*)alloc((size_t)B_*NH_*S_*4);
  bf16* Wbuf = (bf16*)alloc((size_t)B_*NH_*S_*S_*2); // 67 MB decay-weighted scores
  bf16* ybuf = xn;   // xn dead after up-projection
  bf16* vTb  = hb_;
  bf16* obuf = vb_;
  // converted-weight scratch overlapping Wbuf (dead until qk_decay / after pv)
  bf16* xbf    = Wbuf;                               // 4 MB, dead after GEMM1
  bf16* w_in_t = Wbuf + (size_t)T_*IN_;              // 1 MB, dead after GEMM1
  bf16* w_up_t = w_in_t + (size_t)E_*IN_;            // 8 MB, dead after GEMM2
  bf16* w_down_t = Wbuf;                             // written AFTER pv_kernel frees Wbuf

  // 0a. convert x -> bf16 ; transpose+convert w_in, w_up ; zero gate accumulators
  convert_bf16<<<(T_*IN_/8+255)/256, 256, 0, stream>>>(x, xbf, T_*IN_/8);
  transpose_conv_w<<<dim3(E_/64, IN_/64), 256, 0, stream>>>(w_in, w_in_t, IN_, E_);
  transpose_conv_w<<<dim3((2*INNER_)/64, E_/64), 256, 0, stream>>>(w_up, w_up_t, E_, 2*INNER_);
  hipMemsetAsync(igbuf, 0, (size_t)B_*NH_*S_*4, stream);
  hipMemsetAsync(fgbuf, 0, (size_t)B_*NH_*S_*4, stream);
  // 1. h_in = x @ w_in + b_in     (MM=32, NN=8)
  mfma_gemm<<<(T_/128)*(E_/128), 256, 0, stream>>>(xbf, w_in_t, b_in, h_in, IN_, IN_, E_, E_/128);
  // 2. xn = LN(h_in)*ln1_w
  ln_rows<bf16><<<T_, 256, 0, stream>>>(h_in, nullptr, ln1_w, xn);
  // 3. up = xn @ w_up + b_up   (x_m | z)  (MM=32, NN=32)
  mfma_gemm<<<(T_/128)*((2*INNER_)/128), 256, 0, stream>>>(xn, w_up_t, b_up, up, E_, E_, 2*INNER_, (2*INNER_)/128);
  // 4-6 fused: conv+SiLU, q/k/v, gate partial dots (atomic into igbuf/fgbuf)
  conv_headwise<<<(T_*INNER_)/256, 256, 0, stream>>>(up, conv_w, conv_b,
      q_w, q_b, k_w, k_b, v_w, v_b, ig_w, fg_w, xca, qb_, kb_, vb_, igbuf, fgbuf);
  // 7. scans (bias fused): a, M, floor; zero rowsums
  scan8<<<B_*NH_, 256, 0, stream>>>(igbuf, fgbuf, ig_b, fg_b, abuf, Mbuf, flbuf, rsbuf);
  // 8. v -> vT (head-major, d-major)
  transpose_v<<<dim3(S_/64, DH_/64, B_*NH_), 256, 0, stream>>>(vb_, vTb);
  // 9. W = QK^T * scale * decay (64x128 lower-triangle tiles, head XCD-pinned), rowsums
  qk_decay_kernel<<<8*272, 256, 0, stream>>>(qb_, kb_, abuf, Mbuf, rsbuf, Wbuf);
  // 10. O = (W*inv) @ V -> obuf; inv fused, head XCD-pinned, 64-row tiles
  pv_kernel<<<8*128, 256, 0, stream>>>(Wbuf, vTb, rsbuf, flbuf, obuf);
  // 11. headnorm + skip + output gate, written in place over z
  headnorm_gate<<<T_*NH_, 256, 0, stream>>>(obuf, onw, skip, xca, up);
  // 11b. transpose+convert w_down (Wbuf now dead)
  transpose_conv_w<<<dim3(E_/64, INNER_/64), 256, 0, stream>>>(w_down, w_down_t, INNER_, E_);
  // 12. y = h_gated @ w_down + b_down  (MM=32, NN=8)
  mfma_gemm<<<(T_/128)*(E_/128), 256, 0, stream>>>(up + INNER_, w_down_t, b_down, ybuf, INNER_, 2*INNER_, E_, E_/128);
  // 13. out = LN(h_in + y)*post_w
  ln_rows<float><<<T_, 256, 0, stream>>>(h_in, ybuf, post_w, (float*)d_out);
}